// Round 2
// baseline (244.406 us; speedup 1.0000x reference)
//
#include <hip/hip_runtime.h>

// Integrate-and-fire with soft reset, scanned over trailing time axis.
// B=64, D=4096, T=128. rows = B*D = 262144 independent sequential scans.
//
// Strategy: block = 256 threads, each thread owns one row (sequential scan
// is mandatory for exact f32 semantics vs the jax reference). Global memory
// is accessed coalesced by staging 32-timestep chunks through LDS:
//   load tile [256 rows x 32 t] with float4 coalesced -> LDS (stride 33 pad)
//   each thread scans its row's 32 steps in LDS (banks (row+t)%32, 2-way = free)
//   store spikes back coalesced with float4.

#define T_STEPS 128
#define TC 32                 // timesteps per chunk
#define NCHUNK (T_STEPS / TC)
#define ROWS 256              // rows per block (= blockDim.x)
#define LDS_STRIDE 33         // +1 pad: scan-phase banks (row + t) % 32 -> 2-way

__global__ __launch_bounds__(256, 4) void if_encoder_kernel(
    const float* __restrict__ x,      // [rows, T]
    const float* __restrict__ v0,     // [rows]
    const float* __restrict__ thr_p,  // [1]
    float* __restrict__ spikes,       // [rows, T]
    float* __restrict__ vfin,         // [rows]
    int nrows)
{
    __shared__ float tile[ROWS * LDS_STRIDE];

    const int tid = threadIdx.x;
    const int rowbase = blockIdx.x * ROWS;
    const float thr = thr_p[0];

    const int myrow = rowbase + tid;
    float v = (myrow < nrows) ? v0[myrow] : 0.0f;

    for (int c = 0; c < NCHUNK; ++c) {
        // ---- load phase: 256 rows x 32 t = 2048 float4, 8 per thread, coalesced
        #pragma unroll
        for (int it = 0; it < 8; ++it) {
            const int j  = it * 256 + tid;   // float4 index within chunk tile
            const int r  = j >> 3;           // local row
            const int t4 = j & 7;            // float4 slot within the 32-t chunk
            const float4 val = reinterpret_cast<const float4*>(
                x + (size_t)(rowbase + r) * T_STEPS + (size_t)c * TC)[t4];
            float* dst = &tile[r * LDS_STRIDE + t4 * 4];
            dst[0] = val.x; dst[1] = val.y; dst[2] = val.z; dst[3] = val.w;
        }
        __syncthreads();

        // ---- scan phase: thread tid owns local row tid, sequential over t
        {
            float* row = &tile[tid * LDS_STRIDE];
            #pragma unroll
            for (int t = 0; t < TC; ++t) {
                v += row[t];                       // integrate (exact f32 order)
                const bool fired = (v >= thr);
                row[t] = fired ? 1.0f : 0.0f;      // hard 0/1 spike
                v = fired ? (v - thr) : v;         // soft reset
            }
        }
        __syncthreads();

        // ---- store phase: coalesced float4 write of spikes
        #pragma unroll
        for (int it = 0; it < 8; ++it) {
            const int j  = it * 256 + tid;
            const int r  = j >> 3;
            const int t4 = j & 7;
            const float* src = &tile[r * LDS_STRIDE + t4 * 4];
            const float4 val = make_float4(src[0], src[1], src[2], src[3]);
            reinterpret_cast<float4*>(
                spikes + (size_t)(rowbase + r) * T_STEPS + (size_t)c * TC)[t4] = val;
        }
        __syncthreads();   // protect tile before next chunk's load overwrites
    }

    if (myrow < nrows) vfin[myrow] = v;
}

extern "C" void kernel_launch(void* const* d_in, const int* in_sizes, int n_in,
                              void* d_out, int out_size, void* d_ws, size_t ws_size,
                              hipStream_t stream) {
    const float* x     = (const float*)d_in[0];   // input_spikes [64,4096,128]
    const float* v0    = (const float*)d_in[1];   // states [64,4096]
    const float* thr_p = (const float*)d_in[2];   // threshold scalar

    const int nrows = in_sizes[1];                // 64*4096 = 262144
    float* spikes = (float*)d_out;                // [rows, T] first output
    float* vfin   = (float*)d_out + (size_t)nrows * T_STEPS;  // second output

    const int blocks = (nrows + ROWS - 1) / ROWS; // 1024
    if_encoder_kernel<<<blocks, ROWS, 0, stream>>>(x, v0, thr_p, spikes, vfin, nrows);
}